// Round 2
// baseline (1024.933 us; speedup 1.0000x reference)
//
#include <hip/hip_runtime.h>

#define B 4
#define C 48
#define C3 144
#define H 256
#define W 256
#define HW 65536
#define TS 14            // output tile side
#define HS 16            // halo side (TS+2)
#define NT 19            // ceil(256/14)
#define NPIX 196         // TS*TS
#define EPSN 1e-12f

// ---- tiny workspace layout (floats): ~75 KB total ----
#define S_OFF  0
#define NQ_OFF (B * C * C)
#define NK_OFF (NQ_OFF + B * C)
#define M_OFF  (NK_OFF + B * C)
#define ZERO_N (B * C * C + 2 * B * C)   // S + nq + nk get zeroed

__global__ __launch_bounds__(256) void k0_zero(float* __restrict__ ws) {
  const int i = blockIdx.x * 256 + threadIdx.x;
  if (i < ZERO_N) ws[i] = 0.f;
}

// K1: fused 1x1 conv + depthwise 3x3 + Gram/norm accumulation + v routing.
// One block per (batch, 14x14 tile); 256 threads = 16x16 halo positions.
// x channels live in registers; weights via wave-uniform scalar loads.
__global__ __launch_bounds__(256) void k1_fused(
    const float* __restrict__ x, const float* __restrict__ w1,
    const float* __restrict__ w9, float* __restrict__ vout,
    float* __restrict__ S, float* __restrict__ nq, float* __restrict__ nk) {
  __shared__ float qs[4 * 256];        // staging: 4 channels x 16x16 halo
  __shared__ float qt[NPIX * C];       // dwq tile, layout [p][c]
  __shared__ float kt[NPIX * C];       // dwk tile, layout [p][c]
  const int t = threadIdx.x;
  const int bb = blockIdx.x / (NT * NT);
  const int tile = blockIdx.x % (NT * NT);
  const int ty = tile / NT, tx = tile % NT;

  // this thread's halo position
  const int hy = ty * TS - 1 + (t >> 4);
  const int hx = tx * TS - 1 + (t & 15);
  const bool hin = (hy >= 0 && hy < H && hx >= 0 && hx < W);
  const float* xb = x + (size_t)bb * C * HW;
  float xv[C];
#pragma unroll
  for (int ic = 0; ic < C; ++ic)
    xv[ic] = hin ? xb[(size_t)ic * HW + hy * W + hx] : 0.f;

  // this thread's output pixel (threads 196..255 idle in dw phase)
  const int py = t / TS, px = t % TS;
  const int gy = ty * TS + py, gx = tx * TS + px;
  const bool pin = (t < NPIX) && (gy < H) && (gx < W);

  for (int grp = 0; grp < 36; ++grp) {   // 4 channels per group; 144 = 36*4
    const int ch0 = grp * 4;
    const float* wp = w1 + ch0 * C;
    float a0 = 0.f, a1 = 0.f, a2 = 0.f, a3 = 0.f;
#pragma unroll
    for (int ic = 0; ic < C; ++ic) {
      const float xs = xv[ic];
      a0 = fmaf(wp[ic], xs, a0);
      a1 = fmaf(wp[C + ic], xs, a1);
      a2 = fmaf(wp[2 * C + ic], xs, a2);
      a3 = fmaf(wp[3 * C + ic], xs, a3);
    }
    // OOB halo positions got xv==0 -> a==0 == correct zero padding
    qs[0 * 256 + t] = a0;
    qs[1 * 256 + t] = a1;
    qs[2 * 256 + t] = a2;
    qs[3 * 256 + t] = a3;
    __syncthreads();
    if (t < NPIX) {
#pragma unroll
      for (int g = 0; g < 4; ++g) {
        const int ch = ch0 + g;
        const float* w9p = w9 + ch * 9;
        const float* q = qs + g * 256 + py * HS + px;  // 3x3 top-left in halo
        float d = w9p[0] * q[0] + w9p[1] * q[1] + w9p[2] * q[2];
        d = fmaf(w9p[3], q[HS], d);
        d = fmaf(w9p[4], q[HS + 1], d);
        d = fmaf(w9p[5], q[HS + 2], d);
        d = fmaf(w9p[6], q[2 * HS], d);
        d = fmaf(w9p[7], q[2 * HS + 1], d);
        d = fmaf(w9p[8], q[2 * HS + 2], d);
        if (ch < C) {
          qt[t * C + ch] = pin ? d : 0.f;
        } else if (ch < 2 * C) {
          kt[t * C + (ch - C)] = pin ? d : 0.f;
        } else if (pin) {
          vout[((size_t)bb * C + (ch - 2 * C)) * HW + gy * W + gx] = d;
        }
      }
    }
    __syncthreads();   // protect qs before next group's store (also final fence)
  }

  // per-channel sum-of-squares (waves 0 and 1, lanes 0..47)
  if (t < C) {
    float s = 0.f;
    for (int p = 0; p < NPIX; ++p) { const float v = qt[p * C + t]; s = fmaf(v, v, s); }
    atomicAdd(&nq[bb * C + t], s);
  } else if (t >= 64 && t < 64 + C) {
    const int c = t - 64;
    float s = 0.f;
    for (int p = 0; p < NPIX; ++p) { const float v = kt[p * C + c]; s = fmaf(v, v, s); }
    atomicAdd(&nk[bb * C + c], s);
  }

  // Gram: S[c,d] += sum_p q[p,c]*k[p,d]; 6x6 per thread, 4 p-partitions
  {
    const int part = t >> 6;          // wave id
    const int idx = t & 63;
    const int c0 = (idx >> 3) * 6;
    const int d0 = (idx & 7) * 6;
    float acc[6][6] = {{0.f}};
    const int p0 = part * 49;         // 196 = 4*49
    for (int p = p0; p < p0 + 49; ++p) {
      float qv[6], kv[6];
#pragma unroll
      for (int j = 0; j < 6; ++j) {
        qv[j] = qt[p * C + c0 + j];
        kv[j] = kt[p * C + d0 + j];
      }
#pragma unroll
      for (int i = 0; i < 6; ++i)
#pragma unroll
        for (int j = 0; j < 6; ++j)
          acc[i][j] = fmaf(qv[i], kv[j], acc[i][j]);
    }
    float* Sb = S + (size_t)bb * C * C;
#pragma unroll
    for (int i = 0; i < 6; ++i)
#pragma unroll
      for (int j = 0; j < 6; ++j)
        atomicAdd(&Sb[(c0 + i) * C + (d0 + j)], acc[i][j]);
  }
}

// K2: normalize S by row/col L2 norms, * temperature, row softmax, then fold
// the 1x1 proj: M = proj_w @ attn. One block per batch.
__global__ __launch_bounds__(64) void k2_attn(
    const float* __restrict__ S, const float* __restrict__ nq,
    const float* __restrict__ nk, const float* __restrict__ proj_w,
    const float* __restrict__ temperature, float* __restrict__ M) {
  __shared__ float A[C * C];
  __shared__ float knl[C];
  const int bb = blockIdx.x;
  const int t = threadIdx.x;
  const float T = temperature[0];
  if (t < C) knl[t] = fmaxf(sqrtf(nk[bb * C + t]), EPSN);
  __syncthreads();
  if (t < C) {
    const float qn = fmaxf(sqrtf(nq[bb * C + t]), EPSN);
    float row[C];
    float m = -1e30f;
    for (int d = 0; d < C; ++d) {
      const float v = S[(size_t)bb * C * C + t * C + d] / (qn * knl[d]) * T;
      row[d] = v;
      m = fmaxf(m, v);
    }
    float sum = 0.f;
    for (int d = 0; d < C; ++d) { const float e = expf(row[d] - m); row[d] = e; sum += e; }
    const float inv = 1.f / sum;
    for (int d = 0; d < C; ++d) A[t * C + d] = row[d] * inv;
  }
  __syncthreads();
  for (int idx = t; idx < C * C; idx += 64) {
    const int e = idx / C, d = idx % C;
    float acc = 0.f;
    for (int cc = 0; cc < C; ++cc) acc = fmaf(proj_w[e * C + cc], A[cc * C + d], acc);
    M[(size_t)bb * C * C + idx] = acc;
  }
}

// K3: out[e,p] = sum_d M[e,d] * v[d,p], IN-PLACE on d_out (v lives there).
// Each thread owns one pixel column: reads all 48, then writes all 48.
__global__ __launch_bounds__(256) void k3_apply(
    float* __restrict__ out, const float* __restrict__ M) {
  const int t = threadIdx.x;
  const int bb = blockIdx.x >> 8;
  const int p = ((blockIdx.x & 255) << 8) + t;
  float* ob = out + (size_t)bb * C * HW + p;
  const float* Mb = M + (size_t)bb * C * C;
  float vv[C];
#pragma unroll
  for (int d = 0; d < C; ++d) vv[d] = ob[(size_t)d * HW];
  for (int e = 0; e < C; e += 4) {
    const float* m0 = Mb + e * C;
    float a0 = 0.f, a1 = 0.f, a2 = 0.f, a3 = 0.f;
#pragma unroll
    for (int d = 0; d < C; ++d) {
      const float vs = vv[d];
      a0 = fmaf(m0[d], vs, a0);
      a1 = fmaf(m0[C + d], vs, a1);
      a2 = fmaf(m0[2 * C + d], vs, a2);
      a3 = fmaf(m0[3 * C + d], vs, a3);
    }
    ob[(size_t)(e + 0) * HW] = a0;
    ob[(size_t)(e + 1) * HW] = a1;
    ob[(size_t)(e + 2) * HW] = a2;
    ob[(size_t)(e + 3) * HW] = a3;
  }
}

extern "C" void kernel_launch(void* const* d_in, const int* in_sizes, int n_in,
                              void* d_out, int out_size, void* d_ws, size_t ws_size,
                              hipStream_t stream) {
  const float* x      = (const float*)d_in[0];
  const float* qkv_w  = (const float*)d_in[1];
  const float* dw_w   = (const float*)d_in[2];
  const float* proj_w = (const float*)d_in[3];
  const float* temp   = (const float*)d_in[4];
  float* out = (float*)d_out;
  float* ws  = (float*)d_ws;

  float* S  = ws + S_OFF;
  float* nq = ws + NQ_OFF;
  float* nk = ws + NK_OFF;
  float* M  = ws + M_OFF;

  k0_zero<<<(ZERO_N + 255) / 256, 256, 0, stream>>>(ws);
  k1_fused<<<B * NT * NT, 256, 0, stream>>>(x, qkv_w, dw_w, out, S, nq, nk);
  k2_attn<<<B, 64, 0, stream>>>(S, nq, nk, proj_w, temp, M);
  k3_apply<<<B * 256, 256, 0, stream>>>(out, M);
}

// Round 3
// 450.600 us; speedup vs baseline: 2.2746x; 2.2746x over previous
//
#include <hip/hip_runtime.h>

#define B 4
#define C 48
#define C3 144
#define H 256
#define W 256
#define HW 65536
#define TS 14            // output tile side
#define HS 16            // halo side (TS+2)
#define NT 19            // ceil(256/14)
#define NPIX 196         // TS*TS
#define EPSN 1e-12f
#define NCHUNK 64        // gram chunks per batch
#define CHUNK 1024       // pixels per gram chunk

// ================= PATH A workspace layout (floats), ~103 MB =================
#define A_DWQ_OFF  ((size_t)0)
#define A_DWK_OFF  (A_DWQ_OFF + (size_t)B * C * HW)
#define A_SP_OFF   (A_DWK_OFF + (size_t)B * C * HW)            // B*64*2304
#define A_NQP_OFF  (A_SP_OFF + (size_t)B * NCHUNK * C * C)     // B*64*48
#define A_NKP_OFF  (A_NQP_OFF + (size_t)B * NCHUNK * C)
#define A_M_OFF    (A_NKP_OFF + (size_t)B * NCHUNK * C)        // B*2304
#define A_FLOATS   (A_M_OFF + (size_t)B * C * C)

// ================= PATH B (fallback) workspace layout, ~75 KB ================
#define B_S_OFF  0
#define B_NQ_OFF (B * C * C)
#define B_NK_OFF (B_NQ_OFF + B * C)
#define B_M_OFF  (B_NK_OFF + B * C)
#define B_ZERO_N (B * C * C + 2 * B * C)

// ============================ PATH A kernels =================================

// A1: 1x1 conv + depthwise 3x3. One block per (batch, 14x14 tile).
// x channels in registers (1 halo position/thread); weights via wave-uniform
// scalar loads; 8 output channels per group through an 8KB LDS staging tile.
__global__ __launch_bounds__(256) void a1_conv_dw(
    const float* __restrict__ x, const float* __restrict__ w1,
    const float* __restrict__ w9, float* __restrict__ dwq,
    float* __restrict__ dwk, float* __restrict__ vout) {
  __shared__ float qs[8 * 256];
  const int t = threadIdx.x;
  const int bb = blockIdx.x / (NT * NT);
  const int tile = blockIdx.x % (NT * NT);
  const int ty = tile / NT, tx = tile % NT;

  const int hy = ty * TS - 1 + (t >> 4);
  const int hx = tx * TS - 1 + (t & 15);
  const bool hin = (hy >= 0 && hy < H && hx >= 0 && hx < W);
  const float* xb = x + (size_t)bb * C * HW;
  float xv[C];
#pragma unroll
  for (int ic = 0; ic < C; ++ic)
    xv[ic] = hin ? xb[(size_t)ic * HW + hy * W + hx] : 0.f;

  const int py = t / TS, px = t % TS;
  const int gy = ty * TS + py, gx = tx * TS + px;
  const bool pin = (t < NPIX) && (gy < H) && (gx < W);

  for (int grp = 0; grp < 18; ++grp) {      // 8 channels per group
    const int ch0 = grp * 8;
    const float* wp = w1 + ch0 * C;
    float a[8];
#pragma unroll
    for (int g = 0; g < 8; ++g) a[g] = 0.f;
#pragma unroll
    for (int ic = 0; ic < C; ++ic) {
      const float xs = xv[ic];
#pragma unroll
      for (int g = 0; g < 8; ++g) a[g] = fmaf(wp[g * C + ic], xs, a[g]);
    }
#pragma unroll
    for (int g = 0; g < 8; ++g) qs[g * 256 + t] = a[g];  // lane-consecutive
    __syncthreads();
    if (t < NPIX) {
#pragma unroll
      for (int g = 0; g < 8; ++g) {
        const int ch = ch0 + g;
        const float* w9p = w9 + ch * 9;
        const float* q = qs + g * 256 + py * HS + px;
        float d = w9p[0] * q[0] + w9p[1] * q[1] + w9p[2] * q[2];
        d = fmaf(w9p[3], q[HS], d);
        d = fmaf(w9p[4], q[HS + 1], d);
        d = fmaf(w9p[5], q[HS + 2], d);
        d = fmaf(w9p[6], q[2 * HS], d);
        d = fmaf(w9p[7], q[2 * HS + 1], d);
        d = fmaf(w9p[8], q[2 * HS + 2], d);
        if (pin) {
          float* dst;
          int cc;
          if (ch < C)          { dst = dwq; cc = ch; }
          else if (ch < 2 * C) { dst = dwk; cc = ch - C; }
          else                 { dst = vout; cc = ch - 2 * C; }
          dst[((size_t)bb * C + cc) * HW + gy * W + gx] = d;
        }
      }
    }
    __syncthreads();
  }
}

// A2: per-chunk Gram partials + norm partials (no atomics).
// One block per (batch, 1024-pixel chunk); LDS 48x64 panels; 3x3 reg blocking.
__global__ __launch_bounds__(256) void a2_gram(
    const float* __restrict__ dwq, const float* __restrict__ dwk,
    float* __restrict__ Sp, float* __restrict__ nqp, float* __restrict__ nkp) {
  __shared__ float qs[C * 65];
  __shared__ float ks[C * 65];
  const int tid = threadIdx.x;
  const int bb = blockIdx.x / NCHUNK;
  const int chunk = blockIdx.x % NCHUNK;
  const int base = chunk * CHUNK;
  const float* qb = dwq + (size_t)bb * C * HW + base;
  const float* kb = dwk + (size_t)bb * C * HW + base;
  const int c0 = (tid >> 4) * 3;
  const int d0 = (tid & 15) * 3;
  float acc[3][3] = {{0.f}};
  float nacc = 0.f;
  for (int sub = 0; sub < CHUNK / 64; ++sub) {
    __syncthreads();
#pragma unroll
    for (int j = 0; j < 12; ++j) {
      const int idx = tid + j * 256;
      const int cc = idx >> 6;
      const int pp = idx & 63;
      qs[cc * 65 + pp] = qb[(size_t)cc * HW + sub * 64 + pp];
      ks[cc * 65 + pp] = kb[(size_t)cc * HW + sub * 64 + pp];
    }
    __syncthreads();
    if (tid < C) {
#pragma unroll
      for (int pp = 0; pp < 64; ++pp) { const float v = qs[tid * 65 + pp]; nacc = fmaf(v, v, nacc); }
    } else if (tid >= 64 && tid < 64 + C) {
      const int c = tid - 64;
#pragma unroll
      for (int pp = 0; pp < 64; ++pp) { const float v = ks[c * 65 + pp]; nacc = fmaf(v, v, nacc); }
    }
#pragma unroll 8
    for (int pp = 0; pp < 64; ++pp) {
      const float q0 = qs[(c0 + 0) * 65 + pp];
      const float q1 = qs[(c0 + 1) * 65 + pp];
      const float q2 = qs[(c0 + 2) * 65 + pp];
      const float k0 = ks[(d0 + 0) * 65 + pp];
      const float k1 = ks[(d0 + 1) * 65 + pp];
      const float k2 = ks[(d0 + 2) * 65 + pp];
      acc[0][0] = fmaf(q0, k0, acc[0][0]);
      acc[0][1] = fmaf(q0, k1, acc[0][1]);
      acc[0][2] = fmaf(q0, k2, acc[0][2]);
      acc[1][0] = fmaf(q1, k0, acc[1][0]);
      acc[1][1] = fmaf(q1, k1, acc[1][1]);
      acc[1][2] = fmaf(q1, k2, acc[1][2]);
      acc[2][0] = fmaf(q2, k0, acc[2][0]);
      acc[2][1] = fmaf(q2, k1, acc[2][1]);
      acc[2][2] = fmaf(q2, k2, acc[2][2]);
    }
  }
  float* Sb = Sp + ((size_t)bb * NCHUNK + chunk) * C * C;
#pragma unroll
  for (int i = 0; i < 3; ++i)
#pragma unroll
    for (int j = 0; j < 3; ++j)
      Sb[(c0 + i) * C + (d0 + j)] = acc[i][j];
  if (tid < C)                      nqp[((size_t)bb * NCHUNK + chunk) * C + tid] = nacc;
  else if (tid >= 64 && tid < 64 + C) nkp[((size_t)bb * NCHUNK + chunk) * C + (tid - 64)] = nacc;
}

// A3: reduce partials, normalize, softmax, fold proj: M = proj_w @ attn.
__global__ __launch_bounds__(256) void a3_attn(
    const float* __restrict__ Sp, const float* __restrict__ nqp,
    const float* __restrict__ nkp, const float* __restrict__ proj_w,
    const float* __restrict__ temperature, float* __restrict__ M) {
  __shared__ float Sr[C * C];
  __shared__ float qn[C];
  __shared__ float kn[C];
  const int bb = blockIdx.x;
  const int t = threadIdx.x;
  const float T = temperature[0];
  for (int j = t; j < C * C; j += 256) {
    float s = 0.f;
    for (int i = 0; i < NCHUNK; ++i) s += Sp[((size_t)bb * NCHUNK + i) * C * C + j];
    Sr[j] = s;
  }
  if (t < C) {
    float s = 0.f;
    for (int i = 0; i < NCHUNK; ++i) s += nqp[((size_t)bb * NCHUNK + i) * C + t];
    qn[t] = fmaxf(sqrtf(s), EPSN);
  } else if (t >= 64 && t < 64 + C) {
    const int c = t - 64;
    float s = 0.f;
    for (int i = 0; i < NCHUNK; ++i) s += nkp[((size_t)bb * NCHUNK + i) * C + c];
    kn[c] = fmaxf(sqrtf(s), EPSN);
  }
  __syncthreads();
  if (t < C) {
    const float inq = 1.f / qn[t];
    float row[C];
    float m = -1e30f;
    for (int d = 0; d < C; ++d) {
      const float v = Sr[t * C + d] * inq / kn[d] * T;
      row[d] = v;
      m = fmaxf(m, v);
    }
    float sum = 0.f;
    for (int d = 0; d < C; ++d) { const float e = expf(row[d] - m); row[d] = e; sum += e; }
    const float inv = 1.f / sum;
    for (int d = 0; d < C; ++d) Sr[t * C + d] = row[d] * inv;  // in-place (row-local)
  }
  __syncthreads();
  for (int idx = t; idx < C * C; idx += 256) {
    const int e = idx / C, d = idx % C;
    float acc = 0.f;
    for (int cc = 0; cc < C; ++cc) acc = fmaf(proj_w[e * C + cc], Sr[cc * C + d], acc);
    M[(size_t)bb * C * C + idx] = acc;
  }
}

// A4: out[e,p] = sum_d M[e,d]*v[d,p], in place on d_out.
__global__ __launch_bounds__(256) void a4_apply(
    float* __restrict__ out, const float* __restrict__ M) {
  const int t = threadIdx.x;
  const int bb = blockIdx.x >> 8;
  const int p = ((blockIdx.x & 255) << 8) + t;
  float* ob = out + (size_t)bb * C * HW + p;
  const float* Mb = M + (size_t)bb * C * C;
  float vv[C];
#pragma unroll
  for (int d = 0; d < C; ++d) vv[d] = ob[(size_t)d * HW];
  for (int e = 0; e < C; e += 4) {
    const float* m0 = Mb + e * C;
    float a0 = 0.f, a1 = 0.f, a2 = 0.f, a3 = 0.f;
#pragma unroll
    for (int d = 0; d < C; ++d) {
      const float vs = vv[d];
      a0 = fmaf(m0[d], vs, a0);
      a1 = fmaf(m0[C + d], vs, a1);
      a2 = fmaf(m0[2 * C + d], vs, a2);
      a3 = fmaf(m0[3 * C + d], vs, a3);
    }
    ob[(size_t)(e + 0) * HW] = a0;
    ob[(size_t)(e + 1) * HW] = a1;
    ob[(size_t)(e + 2) * HW] = a2;
    ob[(size_t)(e + 3) * HW] = a3;
  }
}

// ==================== PATH B (round-2 fallback) kernels ======================

__global__ __launch_bounds__(256) void k0_zero(float* __restrict__ ws) {
  const int i = blockIdx.x * 256 + threadIdx.x;
  if (i < B_ZERO_N) ws[i] = 0.f;
}

__global__ __launch_bounds__(256) void k1_fused(
    const float* __restrict__ x, const float* __restrict__ w1,
    const float* __restrict__ w9, float* __restrict__ vout,
    float* __restrict__ S, float* __restrict__ nq, float* __restrict__ nk) {
  __shared__ float qs[4 * 256];
  __shared__ float qt[NPIX * C];
  __shared__ float kt[NPIX * C];
  const int t = threadIdx.x;
  const int bb = blockIdx.x / (NT * NT);
  const int tile = blockIdx.x % (NT * NT);
  const int ty = tile / NT, tx = tile % NT;
  const int hy = ty * TS - 1 + (t >> 4);
  const int hx = tx * TS - 1 + (t & 15);
  const bool hin = (hy >= 0 && hy < H && hx >= 0 && hx < W);
  const float* xb = x + (size_t)bb * C * HW;
  float xv[C];
#pragma unroll
  for (int ic = 0; ic < C; ++ic)
    xv[ic] = hin ? xb[(size_t)ic * HW + hy * W + hx] : 0.f;
  const int py = t / TS, px = t % TS;
  const int gy = ty * TS + py, gx = tx * TS + px;
  const bool pin = (t < NPIX) && (gy < H) && (gx < W);
  for (int grp = 0; grp < 36; ++grp) {
    const int ch0 = grp * 4;
    const float* wp = w1 + ch0 * C;
    float a0 = 0.f, a1 = 0.f, a2 = 0.f, a3 = 0.f;
#pragma unroll
    for (int ic = 0; ic < C; ++ic) {
      const float xs = xv[ic];
      a0 = fmaf(wp[ic], xs, a0);
      a1 = fmaf(wp[C + ic], xs, a1);
      a2 = fmaf(wp[2 * C + ic], xs, a2);
      a3 = fmaf(wp[3 * C + ic], xs, a3);
    }
    qs[0 * 256 + t] = a0;
    qs[1 * 256 + t] = a1;
    qs[2 * 256 + t] = a2;
    qs[3 * 256 + t] = a3;
    __syncthreads();
    if (t < NPIX) {
#pragma unroll
      for (int g = 0; g < 4; ++g) {
        const int ch = ch0 + g;
        const float* w9p = w9 + ch * 9;
        const float* q = qs + g * 256 + py * HS + px;
        float d = w9p[0] * q[0] + w9p[1] * q[1] + w9p[2] * q[2];
        d = fmaf(w9p[3], q[HS], d);
        d = fmaf(w9p[4], q[HS + 1], d);
        d = fmaf(w9p[5], q[HS + 2], d);
        d = fmaf(w9p[6], q[2 * HS], d);
        d = fmaf(w9p[7], q[2 * HS + 1], d);
        d = fmaf(w9p[8], q[2 * HS + 2], d);
        if (ch < C)          qt[t * C + ch] = pin ? d : 0.f;
        else if (ch < 2 * C) kt[t * C + (ch - C)] = pin ? d : 0.f;
        else if (pin)        vout[((size_t)bb * C + (ch - 2 * C)) * HW + gy * W + gx] = d;
      }
    }
    __syncthreads();
  }
  if (t < C) {
    float s = 0.f;
    for (int p = 0; p < NPIX; ++p) { const float v = qt[p * C + t]; s = fmaf(v, v, s); }
    atomicAdd(&nq[bb * C + t], s);
  } else if (t >= 64 && t < 64 + C) {
    const int c = t - 64;
    float s = 0.f;
    for (int p = 0; p < NPIX; ++p) { const float v = kt[p * C + c]; s = fmaf(v, v, s); }
    atomicAdd(&nk[bb * C + c], s);
  }
  {
    const int part = t >> 6;
    const int idx = t & 63;
    const int c0 = (idx >> 3) * 6;
    const int d0 = (idx & 7) * 6;
    float acc[6][6] = {{0.f}};
    const int p0 = part * 49;
    for (int p = p0; p < p0 + 49; ++p) {
      float qv[6], kv[6];
#pragma unroll
      for (int j = 0; j < 6; ++j) { qv[j] = qt[p * C + c0 + j]; kv[j] = kt[p * C + d0 + j]; }
#pragma unroll
      for (int i = 0; i < 6; ++i)
#pragma unroll
        for (int j = 0; j < 6; ++j) acc[i][j] = fmaf(qv[i], kv[j], acc[i][j]);
    }
    float* Sb = S + (size_t)bb * C * C;
#pragma unroll
    for (int i = 0; i < 6; ++i)
#pragma unroll
      for (int j = 0; j < 6; ++j) atomicAdd(&Sb[(c0 + i) * C + (d0 + j)], acc[i][j]);
  }
}

__global__ __launch_bounds__(64) void k2_attn_b(
    const float* __restrict__ S, const float* __restrict__ nq,
    const float* __restrict__ nk, const float* __restrict__ proj_w,
    const float* __restrict__ temperature, float* __restrict__ M) {
  __shared__ float A[C * C];
  __shared__ float knl[C];
  const int bb = blockIdx.x;
  const int t = threadIdx.x;
  const float T = temperature[0];
  if (t < C) knl[t] = fmaxf(sqrtf(nk[bb * C + t]), EPSN);
  __syncthreads();
  if (t < C) {
    const float qn = fmaxf(sqrtf(nq[bb * C + t]), EPSN);
    float row[C];
    float m = -1e30f;
    for (int d = 0; d < C; ++d) {
      const float v = S[(size_t)bb * C * C + t * C + d] / (qn * knl[d]) * T;
      row[d] = v;
      m = fmaxf(m, v);
    }
    float sum = 0.f;
    for (int d = 0; d < C; ++d) { const float e = expf(row[d] - m); row[d] = e; sum += e; }
    const float inv = 1.f / sum;
    for (int d = 0; d < C; ++d) A[t * C + d] = row[d] * inv;
  }
  __syncthreads();
  for (int idx = t; idx < C * C; idx += 64) {
    const int e = idx / C, d = idx % C;
    float acc = 0.f;
    for (int cc = 0; cc < C; ++cc) acc = fmaf(proj_w[e * C + cc], A[cc * C + d], acc);
    M[(size_t)bb * C * C + idx] = acc;
  }
}

// =============================================================================

extern "C" void kernel_launch(void* const* d_in, const int* in_sizes, int n_in,
                              void* d_out, int out_size, void* d_ws, size_t ws_size,
                              hipStream_t stream) {
  const float* x      = (const float*)d_in[0];
  const float* qkv_w  = (const float*)d_in[1];
  const float* dw_w   = (const float*)d_in[2];
  const float* proj_w = (const float*)d_in[3];
  const float* temp   = (const float*)d_in[4];
  float* out = (float*)d_out;
  float* ws  = (float*)d_ws;

  if (ws_size >= A_FLOATS * sizeof(float)) {
    // -------- PATH A: split pipeline, no atomics --------
    float* dwq = ws + A_DWQ_OFF;
    float* dwk = ws + A_DWK_OFF;
    float* Sp  = ws + A_SP_OFF;
    float* nqp = ws + A_NQP_OFF;
    float* nkp = ws + A_NKP_OFF;
    float* M   = ws + A_M_OFF;
    a1_conv_dw<<<B * NT * NT, 256, 0, stream>>>(x, qkv_w, dw_w, dwq, dwk, out);
    a2_gram<<<B * NCHUNK, 256, 0, stream>>>(dwq, dwk, Sp, nqp, nkp);
    a3_attn<<<B, 256, 0, stream>>>(Sp, nqp, nkp, proj_w, temp, M);
    a4_apply<<<B * 256, 256, 0, stream>>>(out, M);
  } else {
    // -------- PATH B: round-2 fused fallback --------
    float* S  = ws + B_S_OFF;
    float* nq = ws + B_NQ_OFF;
    float* nk = ws + B_NK_OFF;
    float* M  = ws + B_M_OFF;
    k0_zero<<<(B_ZERO_N + 255) / 256, 256, 0, stream>>>(ws);
    k1_fused<<<B * NT * NT, 256, 0, stream>>>(x, qkv_w, dw_w, out, S, nq, nk);
    k2_attn_b<<<B, 64, 0, stream>>>(S, nq, nk, proj_w, temp, M);
    a4_apply<<<B * 256, 256, 0, stream>>>(out, M);
  }
}